// Round 10
// baseline (960.855 us; speedup 1.0000x reference)
//
#include <hip/hip_runtime.h>

#define TSTEPS 1024

typedef _Float16 half8 __attribute__((ext_vector_type(8)));
typedef _Float16 half4v __attribute__((ext_vector_type(4)));
typedef float    f32x4 __attribute__((ext_vector_type(4)));

#define MFMA16(A_, B_, C_) __builtin_amdgcn_mfma_f32_16x16x32_f16((A_), (B_), (C_), 0, 0, 0)

__device__ __forceinline__ float fast_rcp(float x) { return __builtin_amdgcn_rcpf(x); }
__device__ __forceinline__ float fast_exp2(float x) {
#if __has_builtin(__builtin_amdgcn_exp2f)
    return __builtin_amdgcn_exp2f(x);
#else
    return exp2f(x);
#endif
}

// load 8 consecutive fp32, scale, convert to packed f16 MFMA fragment
__device__ __forceinline__ half8 load_w8s(const float* p, float s) {
    const float4 a = ((const float4*)p)[0];
    const float4 b = ((const float4*)p)[1];
    half8 r;
    r[0] = (_Float16)(s * a.x); r[1] = (_Float16)(s * a.y);
    r[2] = (_Float16)(s * a.z); r[3] = (_Float16)(s * a.w);
    r[4] = (_Float16)(s * b.x); r[5] = (_Float16)(s * b.y);
    r[6] = (_Float16)(s * b.z); r[7] = (_Float16)(s * b.w);
    return r;
}

// Barrier-free 2-wave MFMA GRU. 64 blocks x 16 chains.
//  wave0: GRU1 unit-tiles 0..2 (18 MFMA, 12 triples), owns h1[0:48].
//  wave1: GRU1 tile 3 (6 MFMA, 4 triples) + full GRU2 one step behind
//         (18 MFMA, 8 triples), owns h1[48:64] and h2.
// Sync: per-wave monotone tick flags in LDS. Wave W at tick t spins until
// flag[other] >= t (other finished tick t-1: its reads AND writes drained
// via s_waitcnt lgkmcnt(0) before the flag bump). Parity proof:
//  - reads of h1(t-1) hit buf[(t+1)&1], written by both waves at tick t-1
//    (flag >= t guarantees done).
//  - writes of h1(t) hit buf[t&1]; the other wave's reads of buf[t&1]
//    (= h1(t-2)) happened in its tick t-1, complete before our spin exits.
// Weights pre-scaled: r,z rows by -log2e (v_exp gives e^-a directly);
// n rows by 2*log2e (v_exp gives e^{2an}) -- algebraically exact.
// MFMA layouts (m89/m120-verified): A[m=lane&15][k=quad*8+j],
// B[k=quad*8+j][n=lane&15], C/D: col(n)=lane&15, row(m)=quad*4+reg.
__global__ __launch_bounds__(128, 1)
void gru2_encoder(const float* __restrict__ x,
                  const float* __restrict__ W_ih1,
                  const float* __restrict__ W_hh1,
                  const float* __restrict__ b_ih1,
                  const float* __restrict__ b_hh1,
                  const float* __restrict__ W_ih2,
                  const float* __restrict__ W_hh2,
                  const float* __restrict__ b_ih2,
                  const float* __restrict__ b_hh2,
                  float* __restrict__ out)
{
    const int blk  = blockIdx.x;    // 64 blocks, 16 chains each
    const int tid  = threadIdx.x;   // 128
    const int lane = tid & 63;
    const int wid  = tid >> 6;      // 0..1
    const int nl   = lane & 15;     // chain (B/D column; A row)
    const int quad = lane >> 4;     // 0..3
    const int chain0 = blk * 16;

    const float SNEG = -1.44269504f;       // -log2(e)
    const float SP2  =  2.88539008f;       // 2*log2(e)

    __shared__ __align__(16) _Float16 s_h1[2][16][72];   // [par][chain][unit64+pad] (144B row: 2-way banks, free)
    __shared__ __align__(16) _Float16 s_h2[2][16][40];   // [par][chain][unit32+pad]
    __shared__ __align__(16) _Float16 s_x[TSTEPS][16];   // x f16, [t][chain]
    __shared__ int s_flag[2];

    volatile int* vf = s_flag;

    // ---- one-time staging (the ONLY __syncthreads in the kernel)
    for (int idx = tid; idx < 16 * TSTEPS; idx += 128) {
        const int m = idx >> 10, t = idx & (TSTEPS - 1);
        s_x[t][m] = (_Float16)x[(size_t)(chain0 + m) * TSTEPS + t];
    }
    {
        _Float16* p1 = &s_h1[0][0][0];
        for (int idx = tid; idx < 2 * 16 * 72; idx += 128) p1[idx] = (_Float16)0.0f;
        _Float16* p2 = &s_h2[0][0][0];
        for (int idx = tid; idx < 2 * 16 * 40; idx += 128) p2[idx] = (_Float16)0.0f;
    }
    if (tid < 2) s_flag[tid] = 0;
    __syncthreads();

    if (wid == 0) {
        // ================= WAVE 0 : GRU1 tiles 0..2 =================
        half8 Ar0[3], Ar1[3], Az0[3], Az1[3], An0[3], An1[3];
        f32x4 Cr[3], Cz[3], Cn[3];
        float wxr_s[3][4], wxz_s[3][4], wxn_s[3][4], bNx_s[3][4];
        #pragma unroll
        for (int g = 0; g < 3; ++g) {
            const int ur = g * 16 + nl;
            const int u4 = g * 16 + quad * 4;
            Ar0[g] = load_w8s(W_hh1 + (size_t)(ur)       * 64 + quad * 8,      SNEG);
            Ar1[g] = load_w8s(W_hh1 + (size_t)(ur)       * 64 + 32 + quad * 8, SNEG);
            Az0[g] = load_w8s(W_hh1 + (size_t)(64 + ur)  * 64 + quad * 8,      SNEG);
            Az1[g] = load_w8s(W_hh1 + (size_t)(64 + ur)  * 64 + 32 + quad * 8, SNEG);
            An0[g] = load_w8s(W_hh1 + (size_t)(128 + ur) * 64 + quad * 8,      SP2);
            An1[g] = load_w8s(W_hh1 + (size_t)(128 + ur) * 64 + 32 + quad * 8, SP2);
            const float4 bir = *(const float4*)(b_ih1 + u4);
            const float4 bhr = *(const float4*)(b_hh1 + u4);
            const float4 biz = *(const float4*)(b_ih1 + 64 + u4);
            const float4 bhz = *(const float4*)(b_hh1 + 64 + u4);
            const float4 bin = *(const float4*)(b_ih1 + 128 + u4);
            const float4 bhn = *(const float4*)(b_hh1 + 128 + u4);
            Cr[g] = f32x4{SNEG*(bir.x+bhr.x), SNEG*(bir.y+bhr.y), SNEG*(bir.z+bhr.z), SNEG*(bir.w+bhr.w)};
            Cz[g] = f32x4{SNEG*(biz.x+bhz.x), SNEG*(biz.y+bhz.y), SNEG*(biz.z+bhz.z), SNEG*(biz.w+bhz.w)};
            Cn[g] = f32x4{SP2*bhn.x, SP2*bhn.y, SP2*bhn.z, SP2*bhn.w};
            const float4 wr = *(const float4*)(W_ih1 + u4);
            const float4 wz = *(const float4*)(W_ih1 + 64 + u4);
            const float4 wn = *(const float4*)(W_ih1 + 128 + u4);
            wxr_s[g][0]=SNEG*wr.x; wxr_s[g][1]=SNEG*wr.y; wxr_s[g][2]=SNEG*wr.z; wxr_s[g][3]=SNEG*wr.w;
            wxz_s[g][0]=SNEG*wz.x; wxz_s[g][1]=SNEG*wz.y; wxz_s[g][2]=SNEG*wz.z; wxz_s[g][3]=SNEG*wz.w;
            wxn_s[g][0]=SP2*wn.x;  wxn_s[g][1]=SP2*wn.y;  wxn_s[g][2]=SP2*wn.z;  wxn_s[g][3]=SP2*wn.w;
            bNx_s[g][0]=SP2*bin.x; bNx_s[g][1]=SP2*bin.y; bNx_s[g][2]=SP2*bin.z; bNx_s[g][3]=SP2*bin.w;
        }

        float h1s[3][4] = {};
        for (int t = 0; t < TSTEPS; ++t) {
            while (vf[1] < t) __builtin_amdgcn_s_sleep(1);
            const int pr = (t + 1) & 1;
            const half8 B0 = *(const half8*)&s_h1[pr][nl][quad * 8];
            const half8 B1 = *(const half8*)&s_h1[pr][nl][32 + quad * 8];
            f32x4 aR[3], aZ[3], aN[3];
            #pragma unroll
            for (int g = 0; g < 3; ++g) {
                aR[g] = MFMA16(Ar0[g], B0, Cr[g]); aR[g] = MFMA16(Ar1[g], B1, aR[g]);
                aZ[g] = MFMA16(Az0[g], B0, Cz[g]); aZ[g] = MFMA16(Az1[g], B1, aZ[g]);
                aN[g] = MFMA16(An0[g], B0, Cn[g]); aN[g] = MFMA16(An1[g], B1, aN[g]);
            }
            const float xv = (float)s_x[t][nl];
            #pragma unroll
            for (int g = 0; g < 3; ++g) {
                half4v hv;
                #pragma unroll
                for (int i = 0; i < 4; ++i) {
                    const float ea = fast_exp2(fmaf(wxr_s[g][i], xv, aR[g][i]));  // e^{-ar}
                    const float eb = fast_exp2(fmaf(wxz_s[g][i], xv, aZ[g][i]));  // e^{-az}
                    const float d1 = 1.0f + ea, d2 = 1.0f + eb;
                    const float inv = fast_rcp(d1 * d2);
                    const float r = d2 * inv, z = d1 * inv;
                    const float nx = fmaf(wxn_s[g][i], xv, bNx_s[g][i]);
                    const float ec = fast_exp2(fmaf(r, aN[g][i], nx));            // e^{2an}
                    const float nn = fmaf(-2.0f, fast_rcp(ec + 1.0f), 1.0f);      // tanh
                    h1s[g][i] = nn + z * (h1s[g][i] - nn);
                    hv[i] = (_Float16)h1s[g][i];
                }
                *(half4v*)&s_h1[t & 1][nl][g * 16 + quad * 4] = hv;
            }
            asm volatile("s_waitcnt lgkmcnt(0)" ::: "memory");
            if (lane == 0) vf[0] = t + 1;
        }
    } else {
        // ======= WAVE 1 : GRU1 tile 3 + full GRU2 (one step behind) =======
        // tile3 GRU1
        half8 Tr0, Tr1, Tz0, Tz1, Tn0, Tn1;
        f32x4 TCr, TCz, TCn;
        float twr[4], twz[4], twn[4], tbn[4];
        {
            const int ur = 48 + nl;
            const int u4 = 48 + quad * 4;
            Tr0 = load_w8s(W_hh1 + (size_t)(ur)       * 64 + quad * 8,      SNEG);
            Tr1 = load_w8s(W_hh1 + (size_t)(ur)       * 64 + 32 + quad * 8, SNEG);
            Tz0 = load_w8s(W_hh1 + (size_t)(64 + ur)  * 64 + quad * 8,      SNEG);
            Tz1 = load_w8s(W_hh1 + (size_t)(64 + ur)  * 64 + 32 + quad * 8, SNEG);
            Tn0 = load_w8s(W_hh1 + (size_t)(128 + ur) * 64 + quad * 8,      SP2);
            Tn1 = load_w8s(W_hh1 + (size_t)(128 + ur) * 64 + 32 + quad * 8, SP2);
            const float4 bir = *(const float4*)(b_ih1 + u4);
            const float4 bhr = *(const float4*)(b_hh1 + u4);
            const float4 biz = *(const float4*)(b_ih1 + 64 + u4);
            const float4 bhz = *(const float4*)(b_hh1 + 64 + u4);
            const float4 bin = *(const float4*)(b_ih1 + 128 + u4);
            const float4 bhn = *(const float4*)(b_hh1 + 128 + u4);
            TCr = f32x4{SNEG*(bir.x+bhr.x), SNEG*(bir.y+bhr.y), SNEG*(bir.z+bhr.z), SNEG*(bir.w+bhr.w)};
            TCz = f32x4{SNEG*(biz.x+bhz.x), SNEG*(biz.y+bhz.y), SNEG*(biz.z+bhz.z), SNEG*(biz.w+bhz.w)};
            TCn = f32x4{SP2*bhn.x, SP2*bhn.y, SP2*bhn.z, SP2*bhn.w};
            const float4 wr = *(const float4*)(W_ih1 + u4);
            const float4 wz = *(const float4*)(W_ih1 + 64 + u4);
            const float4 wn = *(const float4*)(W_ih1 + 128 + u4);
            twr[0]=SNEG*wr.x; twr[1]=SNEG*wr.y; twr[2]=SNEG*wr.z; twr[3]=SNEG*wr.w;
            twz[0]=SNEG*wz.x; twz[1]=SNEG*wz.y; twz[2]=SNEG*wz.z; twz[3]=SNEG*wz.w;
            twn[0]=SP2*wn.x;  twn[1]=SP2*wn.y;  twn[2]=SP2*wn.z;  twn[3]=SP2*wn.w;
            tbn[0]=SP2*bin.x; tbn[1]=SP2*bin.y; tbn[2]=SP2*bin.z; tbn[3]=SP2*bin.w;
        }
        // GRU2 (2 unit-tiles)
        half8 IR0[2], IR1[2], IZ0[2], IZ1[2], IN0[2], IN1[2], HR[2], HZ[2], HN[2];
        f32x4 Gr[2], Gz[2], Gnx[2], Gnh[2];
        #pragma unroll
        for (int v = 0; v < 2; ++v) {
            const int vr = v * 16 + nl;
            const int v4 = v * 16 + quad * 4;
            IR0[v] = load_w8s(W_ih2 + (size_t)(vr)      * 64 + quad * 8,      SNEG);
            IR1[v] = load_w8s(W_ih2 + (size_t)(vr)      * 64 + 32 + quad * 8, SNEG);
            IZ0[v] = load_w8s(W_ih2 + (size_t)(32 + vr) * 64 + quad * 8,      SNEG);
            IZ1[v] = load_w8s(W_ih2 + (size_t)(32 + vr) * 64 + 32 + quad * 8, SNEG);
            IN0[v] = load_w8s(W_ih2 + (size_t)(64 + vr) * 64 + quad * 8,      SP2);
            IN1[v] = load_w8s(W_ih2 + (size_t)(64 + vr) * 64 + 32 + quad * 8, SP2);
            HR[v]  = load_w8s(W_hh2 + (size_t)(vr)      * 32 + quad * 8,      SNEG);
            HZ[v]  = load_w8s(W_hh2 + (size_t)(32 + vr) * 32 + quad * 8,      SNEG);
            HN[v]  = load_w8s(W_hh2 + (size_t)(64 + vr) * 32 + quad * 8,      SP2);
            const float4 bir = *(const float4*)(b_ih2 + v4);
            const float4 bhr = *(const float4*)(b_hh2 + v4);
            const float4 biz = *(const float4*)(b_ih2 + 32 + v4);
            const float4 bhz = *(const float4*)(b_hh2 + 32 + v4);
            const float4 bin = *(const float4*)(b_ih2 + 64 + v4);
            const float4 bhn = *(const float4*)(b_hh2 + 64 + v4);
            Gr[v]  = f32x4{SNEG*(bir.x+bhr.x), SNEG*(bir.y+bhr.y), SNEG*(bir.z+bhr.z), SNEG*(bir.w+bhr.w)};
            Gz[v]  = f32x4{SNEG*(biz.x+bhz.x), SNEG*(biz.y+bhz.y), SNEG*(biz.z+bhz.z), SNEG*(biz.w+bhz.w)};
            Gnx[v] = f32x4{SP2*bin.x, SP2*bin.y, SP2*bin.z, SP2*bin.w};
            Gnh[v] = f32x4{SP2*bhn.x, SP2*bhn.y, SP2*bhn.z, SP2*bhn.w};
        }

        float h1t[4] = {};
        float h2s[2][4] = {};
        for (int t = 0; t <= TSTEPS; ++t) {
            while (vf[0] < t) __builtin_amdgcn_s_sleep(1);
            const int pr = (t + 1) & 1;
            const half8 B0 = *(const half8*)&s_h1[pr][nl][quad * 8];
            const half8 B1 = *(const half8*)&s_h1[pr][nl][32 + quad * 8];
            if (t < TSTEPS) {
                // GRU1 tile 3
                f32x4 aR = MFMA16(Tr0, B0, TCr); aR = MFMA16(Tr1, B1, aR);
                f32x4 aZ = MFMA16(Tz0, B0, TCz); aZ = MFMA16(Tz1, B1, aZ);
                f32x4 aN = MFMA16(Tn0, B0, TCn); aN = MFMA16(Tn1, B1, aN);
                const float xv = (float)s_x[t][nl];
                half4v hv;
                #pragma unroll
                for (int i = 0; i < 4; ++i) {
                    const float ea = fast_exp2(fmaf(twr[i], xv, aR[i]));
                    const float eb = fast_exp2(fmaf(twz[i], xv, aZ[i]));
                    const float d1 = 1.0f + ea, d2 = 1.0f + eb;
                    const float inv = fast_rcp(d1 * d2);
                    const float r = d2 * inv, z = d1 * inv;
                    const float nx = fmaf(twn[i], xv, tbn[i]);
                    const float ec = fast_exp2(fmaf(r, aN[i], nx));
                    const float nn = fmaf(-2.0f, fast_rcp(ec + 1.0f), 1.0f);
                    h1t[i] = nn + z * (h1t[i] - nn);
                    hv[i] = (_Float16)h1t[i];
                }
                *(half4v*)&s_h1[t & 1][nl][48 + quad * 4] = hv;
            }
            if (t >= 1) {
                // GRU2 step t-1: h1(t-1) (B0/B1) + h2(t-2)
                const half8 Bh = *(const half8*)&s_h2[t & 1][nl][quad * 8];
                #pragma unroll
                for (int v = 0; v < 2; ++v) {
                    f32x4 aR = MFMA16(IR0[v], B0, Gr[v]);  aR = MFMA16(IR1[v], B1, aR);
                    aR = MFMA16(HR[v], Bh, aR);
                    f32x4 aZ = MFMA16(IZ0[v], B0, Gz[v]);  aZ = MFMA16(IZ1[v], B1, aZ);
                    aZ = MFMA16(HZ[v], Bh, aZ);
                    f32x4 aNx = MFMA16(IN0[v], B0, Gnx[v]); aNx = MFMA16(IN1[v], B1, aNx);
                    f32x4 aNh = MFMA16(HN[v], Bh, Gnh[v]);
                    half4v hv;
                    #pragma unroll
                    for (int i = 0; i < 4; ++i) {
                        const float ea = fast_exp2(aR[i]);
                        const float eb = fast_exp2(aZ[i]);
                        const float d1 = 1.0f + ea, d2 = 1.0f + eb;
                        const float inv = fast_rcp(d1 * d2);
                        const float r2 = d2 * inv, z2 = d1 * inv;
                        const float ec = fast_exp2(fmaf(r2, aNh[i], aNx[i]));
                        const float n2 = fmaf(-2.0f, fast_rcp(ec + 1.0f), 1.0f);
                        h2s[v][i] = n2 + z2 * (h2s[v][i] - n2);
                        hv[i] = (_Float16)h2s[v][i];
                    }
                    *(half4v*)&s_h2[(t + 1) & 1][nl][v * 16 + quad * 4] = hv;
                }
            }
            asm volatile("s_waitcnt lgkmcnt(0)" ::: "memory");
            if (lane == 0) vf[1] = t + 1;
        }

        #pragma unroll
        for (int v = 0; v < 2; ++v) {
            float4 o = {h2s[v][0], h2s[v][1], h2s[v][2], h2s[v][3]};
            *(float4*)(out + (size_t)(chain0 + nl) * 32 + v * 16 + quad * 4) = o;
        }
    }
}

extern "C" void kernel_launch(void* const* d_in, const int* in_sizes, int n_in,
                              void* d_out, int out_size, void* d_ws, size_t ws_size,
                              hipStream_t stream) {
    const float* x     = (const float*)d_in[0];
    const float* W_ih1 = (const float*)d_in[1];
    const float* W_hh1 = (const float*)d_in[2];
    const float* b_ih1 = (const float*)d_in[3];
    const float* b_hh1 = (const float*)d_in[4];
    const float* W_ih2 = (const float*)d_in[5];
    const float* W_hh2 = (const float*)d_in[6];
    const float* b_ih2 = (const float*)d_in[7];
    const float* b_hh2 = (const float*)d_in[8];
    float* out = (float*)d_out;

    gru2_encoder<<<dim3(64), dim3(128), 0, stream>>>(
        x, W_ih1, W_hh1, b_ih1, b_hh1, W_ih2, W_hh2, b_ih2, b_hh2, out);
}

// Round 11
// 672.841 us; speedup vs baseline: 1.4281x; 1.4281x over previous
//
#include <hip/hip_runtime.h>

#define TSTEPS 1024

typedef _Float16 half8 __attribute__((ext_vector_type(8)));
typedef _Float16 half4v __attribute__((ext_vector_type(4)));
typedef float    f32x4 __attribute__((ext_vector_type(4)));

#define MFMA16(A_, B_, C_) __builtin_amdgcn_mfma_f32_16x16x32_f16((A_), (B_), (C_), 0, 0, 0)

__device__ __forceinline__ float fast_rcp(float x) { return __builtin_amdgcn_rcpf(x); }
__device__ __forceinline__ float fast_exp2(float x) {
#if __has_builtin(__builtin_amdgcn_exp2f)
    return __builtin_amdgcn_exp2f(x);
#else
    return exp2f(x);
#endif
}

// load 8 consecutive fp32, scale, convert to packed f16 MFMA fragment
__device__ __forceinline__ half8 load_w8s(const float* p, float s) {
    const float4 a = ((const float4*)p)[0];
    const float4 b = ((const float4*)p)[1];
    half8 r;
    r[0] = (_Float16)(s * a.x); r[1] = (_Float16)(s * a.y);
    r[2] = (_Float16)(s * a.z); r[3] = (_Float16)(s * a.w);
    r[4] = (_Float16)(s * b.x); r[5] = (_Float16)(s * b.y);
    r[6] = (_Float16)(s * b.z); r[7] = (_Float16)(s * b.w);
    return r;
}

// MFMA 2-layer GRU, 64 blocks x 16 chains, FOUR waves (one per SIMD -- the
// point: R8 put 6 waves on 4 SIMDs and the doubled SIMDs serialized two
// waves' issue; quarter-rate transcendentals (~8cyc/wave) make each gate
// triple ~56 cyc, so co-residency was the critical path).
//   wave w (0..3): GRU1 unit-tile w: 6 MFMA + 4 triples.
//   waves 0,1:     + GRU2 unit-tile w, ONE STEP BEHIND: 9 MFMA + 4 triples.
//                  (reuses the same B0/B1 h1-fragments read for GRU1)
// One __syncthreads per tick. Gate math in exp2 form with pre-scaled
// weights (r,z rows by -log2e; n rows by 2*log2e) -- validated in R10
// (same absmax as fmaf/expf path).
// MFMA layouts (m89/m120-verified): A[m=lane&15][k=quad*8+j],
// B[k=quad*8+j][n=lane&15], C/D: col(n)=lane&15, row(m)=quad*4+reg.
// h-parity: at tick t, h1(t-1) is in s_h1[(t+1)&1]; GRU2 reads h2(t-2)
// from s_h2[t&1] and writes h2(t-1) to s_h2[(t+1)&1]  (R8 scheme).
__global__ __launch_bounds__(256, 1)
void gru2_encoder(const float* __restrict__ x,
                  const float* __restrict__ W_ih1,
                  const float* __restrict__ W_hh1,
                  const float* __restrict__ b_ih1,
                  const float* __restrict__ b_hh1,
                  const float* __restrict__ W_ih2,
                  const float* __restrict__ W_hh2,
                  const float* __restrict__ b_ih2,
                  const float* __restrict__ b_hh2,
                  float* __restrict__ out)
{
    const int blk  = blockIdx.x;    // 64 blocks, 16 chains each
    const int tid  = threadIdx.x;   // 256
    const int lane = tid & 63;
    const int wid  = tid >> 6;      // 0..3
    const int nl   = lane & 15;     // chain (B/D column; A row)
    const int quad = lane >> 4;     // 0..3
    const int chain0 = blk * 16;

    const float SNEG = -1.44269504f;       // -log2(e)
    const float SP2  =  2.88539008f;       // 2*log2(e)

    __shared__ __align__(16) _Float16 s_h1[2][16][72];   // [par][chain][unit64+pad]
    __shared__ __align__(16) _Float16 s_h2[2][16][40];   // [par][chain][unit32+pad]
    __shared__ __align__(16) _Float16 s_x[TSTEPS][16];   // x f16, [t][chain]

    // ---- one-time staging
    for (int idx = tid; idx < 16 * TSTEPS; idx += 256) {
        const int m = idx >> 10, t = idx & (TSTEPS - 1);
        s_x[t][m] = (_Float16)x[(size_t)(chain0 + m) * TSTEPS + t];
    }
    {
        _Float16* p1 = &s_h1[0][0][0];
        for (int idx = tid; idx < 2 * 16 * 72; idx += 256) p1[idx] = (_Float16)0.0f;
        _Float16* p2 = &s_h2[0][0][0];
        for (int idx = tid; idx < 2 * 16 * 40; idx += 256) p2[idx] = (_Float16)0.0f;
    }
    __syncthreads();

    // ======== GRU1 tile wid (all waves) ========
    half8 Ar0, Ar1, Az0, Az1, An0, An1;
    f32x4 Cr, Cz, Cn;
    float twr[4], twz[4], twn[4], tbn[4];
    {
        const int ur = wid * 16 + nl;
        const int u4 = wid * 16 + quad * 4;
        Ar0 = load_w8s(W_hh1 + (size_t)(ur)       * 64 + quad * 8,      SNEG);
        Ar1 = load_w8s(W_hh1 + (size_t)(ur)       * 64 + 32 + quad * 8, SNEG);
        Az0 = load_w8s(W_hh1 + (size_t)(64 + ur)  * 64 + quad * 8,      SNEG);
        Az1 = load_w8s(W_hh1 + (size_t)(64 + ur)  * 64 + 32 + quad * 8, SNEG);
        An0 = load_w8s(W_hh1 + (size_t)(128 + ur) * 64 + quad * 8,      SP2);
        An1 = load_w8s(W_hh1 + (size_t)(128 + ur) * 64 + 32 + quad * 8, SP2);
        const float4 bir = *(const float4*)(b_ih1 + u4);
        const float4 bhr = *(const float4*)(b_hh1 + u4);
        const float4 biz = *(const float4*)(b_ih1 + 64 + u4);
        const float4 bhz = *(const float4*)(b_hh1 + 64 + u4);
        const float4 bin = *(const float4*)(b_ih1 + 128 + u4);
        const float4 bhn = *(const float4*)(b_hh1 + 128 + u4);
        Cr = f32x4{SNEG*(bir.x+bhr.x), SNEG*(bir.y+bhr.y), SNEG*(bir.z+bhr.z), SNEG*(bir.w+bhr.w)};
        Cz = f32x4{SNEG*(biz.x+bhz.x), SNEG*(biz.y+bhz.y), SNEG*(biz.z+bhz.z), SNEG*(biz.w+bhz.w)};
        Cn = f32x4{SP2*bhn.x, SP2*bhn.y, SP2*bhn.z, SP2*bhn.w};
        const float4 wr = *(const float4*)(W_ih1 + u4);
        const float4 wz = *(const float4*)(W_ih1 + 64 + u4);
        const float4 wn = *(const float4*)(W_ih1 + 128 + u4);
        twr[0]=SNEG*wr.x; twr[1]=SNEG*wr.y; twr[2]=SNEG*wr.z; twr[3]=SNEG*wr.w;
        twz[0]=SNEG*wz.x; twz[1]=SNEG*wz.y; twz[2]=SNEG*wz.z; twz[3]=SNEG*wz.w;
        twn[0]=SP2*wn.x;  twn[1]=SP2*wn.y;  twn[2]=SP2*wn.z;  twn[3]=SP2*wn.w;
        tbn[0]=SP2*bin.x; tbn[1]=SP2*bin.y; tbn[2]=SP2*bin.z; tbn[3]=SP2*bin.w;
    }

    // ======== GRU2 tile wid (waves 0,1 only) ========
    half8 IR0, IR1, IZ0, IZ1, IN0, IN1, HR, HZ, HN;
    f32x4 Gr, Gz, Gnx, Gnh;
    if (wid < 2) {
        const int vr = wid * 16 + nl;
        const int v4 = wid * 16 + quad * 4;
        IR0 = load_w8s(W_ih2 + (size_t)(vr)      * 64 + quad * 8,      SNEG);
        IR1 = load_w8s(W_ih2 + (size_t)(vr)      * 64 + 32 + quad * 8, SNEG);
        IZ0 = load_w8s(W_ih2 + (size_t)(32 + vr) * 64 + quad * 8,      SNEG);
        IZ1 = load_w8s(W_ih2 + (size_t)(32 + vr) * 64 + 32 + quad * 8, SNEG);
        IN0 = load_w8s(W_ih2 + (size_t)(64 + vr) * 64 + quad * 8,      SP2);
        IN1 = load_w8s(W_ih2 + (size_t)(64 + vr) * 64 + 32 + quad * 8, SP2);
        HR  = load_w8s(W_hh2 + (size_t)(vr)      * 32 + quad * 8,      SNEG);
        HZ  = load_w8s(W_hh2 + (size_t)(32 + vr) * 32 + quad * 8,      SNEG);
        HN  = load_w8s(W_hh2 + (size_t)(64 + vr) * 32 + quad * 8,      SP2);
        const float4 bir = *(const float4*)(b_ih2 + v4);
        const float4 bhr = *(const float4*)(b_hh2 + v4);
        const float4 biz = *(const float4*)(b_ih2 + 32 + v4);
        const float4 bhz = *(const float4*)(b_hh2 + 32 + v4);
        const float4 bin = *(const float4*)(b_ih2 + 64 + v4);
        const float4 bhn = *(const float4*)(b_hh2 + 64 + v4);
        Gr  = f32x4{SNEG*(bir.x+bhr.x), SNEG*(bir.y+bhr.y), SNEG*(bir.z+bhr.z), SNEG*(bir.w+bhr.w)};
        Gz  = f32x4{SNEG*(biz.x+bhz.x), SNEG*(biz.y+bhz.y), SNEG*(biz.z+bhz.z), SNEG*(biz.w+bhz.w)};
        Gnx = f32x4{SP2*bin.x, SP2*bin.y, SP2*bin.z, SP2*bin.w};
        Gnh = f32x4{SP2*bhn.x, SP2*bhn.y, SP2*bhn.z, SP2*bhn.w};
    }

    float h1s[4] = {};
    float h2s[4] = {};

    for (int t = 0; t <= TSTEPS; ++t) {
        const int pr = (t + 1) & 1;            // parity holding h1(t-1)
        // B fragments of h1(t-1): shared by GRU1 (this tick) and GRU2 (one behind)
        const half8 B0 = *(const half8*)&s_h1[pr][nl][quad * 8];
        const half8 B1 = *(const half8*)&s_h1[pr][nl][32 + quad * 8];

        if (t < TSTEPS) {
            // ---- GRU1 step t ----
            f32x4 aR = MFMA16(Ar0, B0, Cr); aR = MFMA16(Ar1, B1, aR);
            f32x4 aZ = MFMA16(Az0, B0, Cz); aZ = MFMA16(Az1, B1, aZ);
            f32x4 aN = MFMA16(An0, B0, Cn); aN = MFMA16(An1, B1, aN);
            const float xv = (float)s_x[t][nl];
            half4v hv;
            #pragma unroll
            for (int i = 0; i < 4; ++i) {
                const float ea = fast_exp2(fmaf(twr[i], xv, aR[i]));   // e^{-ar}
                const float eb = fast_exp2(fmaf(twz[i], xv, aZ[i]));   // e^{-az}
                const float d1 = 1.0f + ea, d2 = 1.0f + eb;
                const float inv = fast_rcp(d1 * d2);
                const float r = d2 * inv, z = d1 * inv;
                const float nx = fmaf(twn[i], xv, tbn[i]);
                const float ec = fast_exp2(fmaf(r, aN[i], nx));        // e^{2an}
                const float nn = fmaf(-2.0f, fast_rcp(ec + 1.0f), 1.0f);
                h1s[i] = nn + z * (h1s[i] - nn);
                hv[i] = (_Float16)h1s[i];
            }
            *(half4v*)&s_h1[t & 1][nl][wid * 16 + quad * 4] = hv;
        }

        if (wid < 2 && t >= 1) {
            // ---- GRU2 step t-1: h1(t-1) via B0/B1, h2(t-2) via Bh ----
            const half8 Bh = *(const half8*)&s_h2[t & 1][nl][quad * 8];
            f32x4 aR = MFMA16(IR0, B0, Gr);  aR = MFMA16(IR1, B1, aR);
            aR = MFMA16(HR, Bh, aR);
            f32x4 aZ = MFMA16(IZ0, B0, Gz);  aZ = MFMA16(IZ1, B1, aZ);
            aZ = MFMA16(HZ, Bh, aZ);
            f32x4 aNx = MFMA16(IN0, B0, Gnx); aNx = MFMA16(IN1, B1, aNx);
            f32x4 aNh = MFMA16(HN, Bh, Gnh);
            half4v hv;
            #pragma unroll
            for (int i = 0; i < 4; ++i) {
                const float ea = fast_exp2(aR[i]);
                const float eb = fast_exp2(aZ[i]);
                const float d1 = 1.0f + ea, d2 = 1.0f + eb;
                const float inv = fast_rcp(d1 * d2);
                const float r2 = d2 * inv, z2 = d1 * inv;
                const float ec = fast_exp2(fmaf(r2, aNh[i], aNx[i]));
                const float n2 = fmaf(-2.0f, fast_rcp(ec + 1.0f), 1.0f);
                h2s[i] = n2 + z2 * (h2s[i] - n2);
                hv[i] = (_Float16)h2s[i];
            }
            *(half4v*)&s_h2[(t + 1) & 1][nl][wid * 16 + quad * 4] = hv;  // h2(t-1)
        }
        __syncthreads();
    }

    if (wid < 2) {
        float4 o = {h2s[0], h2s[1], h2s[2], h2s[3]};
        *(float4*)(out + (size_t)(chain0 + nl) * 32 + wid * 16 + quad * 4) = o;
    }
}

extern "C" void kernel_launch(void* const* d_in, const int* in_sizes, int n_in,
                              void* d_out, int out_size, void* d_ws, size_t ws_size,
                              hipStream_t stream) {
    const float* x     = (const float*)d_in[0];
    const float* W_ih1 = (const float*)d_in[1];
    const float* W_hh1 = (const float*)d_in[2];
    const float* b_ih1 = (const float*)d_in[3];
    const float* b_hh1 = (const float*)d_in[4];
    const float* W_ih2 = (const float*)d_in[5];
    const float* W_hh2 = (const float*)d_in[6];
    const float* b_ih2 = (const float*)d_in[7];
    const float* b_hh2 = (const float*)d_in[8];
    float* out = (float*)d_out;

    gru2_encoder<<<dim3(64), dim3(256), 0, stream>>>(
        x, W_ih1, W_hh1, b_ih1, b_hh1, W_ih2, W_hh2, b_ih2, b_hh2, out);
}